// Round 11
// baseline (519.750 us; speedup 1.0000x reference)
//
#include <hip/hip_runtime.h>
#include <hip/hip_bf16.h>
#include <math.h>

#define NH 32
#define NKV 8
#define HD 64
#define B_ 2
#define S_ 2048
#define E_ 2048
#define M_ 4096   // B_*S_

typedef unsigned short ushort_t;
typedef __attribute__((ext_vector_type(8))) short short8;
typedef __attribute__((ext_vector_type(4))) short short4v;
typedef __attribute__((ext_vector_type(4))) float floatx4;

__device__ inline unsigned short f2bf(float f) {          // RNE (pre-pass quality)
  unsigned int u = __float_as_uint(f);
  return (unsigned short)((u + 0x7FFFu + ((u >> 16) & 1u)) >> 16);
}
__device__ inline unsigned short f2bfc(float f) {         // cheap round-half-up (hot path)
  return (unsigned short)((__float_as_uint(f) + 0x8000u) >> 16);
}

// async global->LDS, 16B per lane; lds base wave-uniform (HW adds lane*16)
__device__ inline void ld_lds16(const void* g, void* l) {
  __builtin_amdgcn_global_load_lds((__attribute__((address_space(1))) void*)g,
                                   (__attribute__((address_space(3))) void*)l, 16, 0, 0);
}

// ---------------- x fp32 -> bf16 ----------------
__global__ __launch_bounds__(256) void cast_x(const float* __restrict__ x,
                                              ushort_t* __restrict__ xb) {
  size_t i = ((size_t)blockIdx.x * 256 + threadIdx.x) * 8;
  float4 a = *(const float4*)(x + i);
  float4 b = *(const float4*)(x + i + 4);
  short8 o;
  o[0] = (short)f2bf(a.x); o[1] = (short)f2bf(a.y);
  o[2] = (short)f2bf(a.z); o[3] = (short)f2bf(a.w);
  o[4] = (short)f2bf(b.x); o[5] = (short)f2bf(b.y);
  o[6] = (short)f2bf(b.z); o[7] = (short)f2bf(b.w);
  *(short8*)(xb + i) = o;
}

// ---------------- all 4 weight transposes in ONE launch ----------------
// (R=2048 rows for all). x<64: Wq->WT; 64..79: Wk->WT+2048*2048; 80..95: Wv->WT+2560*2048;
// 96..159: Wo->WoT.
__global__ __launch_bounds__(256) void transpose_all(const float* __restrict__ Wq,
                                                     const float* __restrict__ Wk,
                                                     const float* __restrict__ Wv,
                                                     const float* __restrict__ Wo,
                                                     ushort_t* __restrict__ WT,
                                                     ushort_t* __restrict__ WoT) {
  __shared__ float tile[32][33];
  int bx = blockIdx.x;
  const float* in; ushort_t* out; int C, cx;
  if (bx < 64)       { in = Wq; out = WT;                ;  C = 2048; cx = bx; }
  else if (bx < 80)  { in = Wk; out = WT + 2048 * 2048;  C = 512;  cx = bx - 64; }
  else if (bx < 96)  { in = Wv; out = WT + 2560 * 2048;  C = 512;  cx = bx - 80; }
  else               { in = Wo; out = WoT;               C = 2048; cx = bx - 96; }
  const int R = 2048;
  int c0 = cx * 32, r0 = blockIdx.y * 32;
  int x = threadIdx.x, y0 = threadIdx.y;  // block (32,8)
  for (int i = 0; i < 4; i++) {
    int r = y0 + i * 8;
    tile[r][x] = in[(size_t)(r0 + r) * C + c0 + x];
  }
  __syncthreads();
  for (int i = 0; i < 4; i++) {
    int r = y0 + i * 8;
    out[(size_t)(c0 + r) * R + r0 + x] = f2bf(tile[x][r]);
  }
}

// ---------------- outv (B,NKV,S,HD) fp32 -> vt (B,NKV,HD,S) bf16 ----------------
__global__ __launch_bounds__(256) void transpose_v(const float* __restrict__ outv,
                                                   ushort_t* __restrict__ vt) {
  __shared__ float t64[64][65];
  int bg = blockIdx.y;        // 0..15
  int s0 = blockIdx.x * 64;   // 32 s-tiles
  int tid = threadIdx.x;
  size_t ibase = (size_t)bg * S_ * HD + (size_t)s0 * HD;
  for (int i = tid; i < 1024; i += 256) {
    int sr = i >> 4, dc = (i & 15) * 4;
    float4 v = *(const float4*)(outv + ibase + (size_t)sr * HD + dc);
    t64[sr][dc] = v.x; t64[sr][dc + 1] = v.y; t64[sr][dc + 2] = v.z; t64[sr][dc + 3] = v.w;
  }
  __syncthreads();
  size_t obase = (size_t)bg * HD * S_ + s0;
  for (int i = tid; i < 512; i += 256) {
    int d = i >> 3, ss = (i & 7) * 8;
    short8 o;
#pragma unroll
    for (int e = 0; e < 8; e++) o[e] = (short)f2bf(t64[ss + e][d]);
    *(short8*)(vt + obase + (size_t)d * S_ + ss) = o;
  }
}

// ---------------- fused QKV GEMM (unchanged from round 10) ----------------
__global__ __launch_bounds__(256) void gemm_qkv(const ushort_t* __restrict__ xb,
                                                const ushort_t* __restrict__ WT,
                                                ushort_t* __restrict__ qbf,
                                                float* __restrict__ outk,
                                                ushort_t* __restrict__ kbf,
                                                float* __restrict__ outv,
                                                const float* __restrict__ cosP,
                                                const float* __restrict__ sinP) {
  __shared__ __align__(16) ushort_t As[128][32];
  __shared__ __align__(16) ushort_t Bs[128][32];
  const int K = 2048;
  int tid = threadIdx.x;
  int m0 = blockIdx.y * 128, n0 = blockIdx.x * 128;
  int w = tid >> 6, lane = tid & 63;
  int wm = (w >> 1) * 64, wn = (w & 1) * 64;
  int lr = lane & 15, quad = lane >> 4;
  int srow = lane >> 2, soff = (lane & 3) * 16;
  floatx4 acc[4][4] = {};
  for (int kt = 0; kt < 64; kt++) {
    __syncthreads();
#pragma unroll
    for (int j = 0; j < 2; j++) {
      int r = j * 64 + w * 16;
      ld_lds16((const char*)(xb + (size_t)(m0 + r + srow) * K) + kt * 64 + soff,
               (char*)As + r * 64);
      ld_lds16((const char*)(WT + (size_t)(n0 + r + srow) * K) + kt * 64 + soff,
               (char*)Bs + r * 64);
    }
    __syncthreads();
    short8 af[4], bf[4];
#pragma unroll
    for (int i = 0; i < 4; i++) af[i] = *(const short8*)(&As[wm + i * 16 + lr][quad * 8]);
#pragma unroll
    for (int j = 0; j < 4; j++) bf[j] = *(const short8*)(&Bs[wn + j * 16 + lr][quad * 8]);
#pragma unroll
    for (int i = 0; i < 4; i++)
#pragma unroll
      for (int j = 0; j < 4; j++)
        acc[i][j] = __builtin_amdgcn_mfma_f32_16x16x32_bf16(af[i], bf[j], acc[i][j], 0, 0, 0);
  }
  if (n0 < 2048) {  // Q + rope -> qbf
#pragma unroll
    for (int i = 0; i < 4; i++)
#pragma unroll
      for (int j = 0; j < 2; j++) {
        int d = j * 16 + lr;
#pragma unroll
        for (int r = 0; r < 4; r++) {
          int row = m0 + wm + i * 16 + quad * 4 + r;
          int s = row & (S_ - 1);
          float c = cosP[s * 64 + d], sn = sinP[s * 64 + d];
          float x1 = acc[i][j][r], x2 = acc[i][j + 2][r];
          size_t o = (size_t)row * 2048 + n0 + wn + d;
          qbf[o] = f2bf(x1 * c - x2 * sn);
          qbf[o + 32] = f2bf(x2 * c + x1 * sn);
        }
      }
  } else if (n0 < 2560) {  // K + rope -> outk fp32 + kbf bf16
    int h = (n0 - 2048 + wn) >> 6;
#pragma unroll
    for (int i = 0; i < 4; i++)
#pragma unroll
      for (int j = 0; j < 2; j++) {
        int d = j * 16 + lr;
#pragma unroll
        for (int r = 0; r < 4; r++) {
          int row = m0 + wm + i * 16 + quad * 4 + r;
          int s = row & (S_ - 1), b = row >> 11;
          float c = cosP[s * 64 + d], sn = sinP[s * 64 + d];
          float x1 = acc[i][j][r], x2 = acc[i][j + 2][r];
          float y1 = x1 * c - x2 * sn, y2 = x2 * c + x1 * sn;
          size_t o = ((size_t)(b * NKV + h) * S_ + s) * 64 + d;
          outk[o] = y1; outk[o + 32] = y2;
          kbf[o] = f2bf(y1); kbf[o + 32] = f2bf(y2);
        }
      }
  } else {  // V -> outv fp32
    int h = (n0 - 2560 + wn) >> 6;
#pragma unroll
    for (int i = 0; i < 4; i++)
#pragma unroll
      for (int j = 0; j < 4; j++) {
        int d = j * 16 + lr;
#pragma unroll
        for (int r = 0; r < 4; r++) {
          int row = m0 + wm + i * 16 + quad * 4 + r;
          int s = row & (S_ - 1), b = row >> 11;
          outv[((size_t)(b * NKV + h) * S_ + s) * 64 + d] = acc[i][j][r];
        }
      }
  }
}

// ---------------- O GEMM (unchanged from round 10) ----------------
__global__ __launch_bounds__(256) void gemm_o(const ushort_t* __restrict__ ctx,
                                              const ushort_t* __restrict__ WoT,
                                              float* __restrict__ y) {
  __shared__ __align__(16) ushort_t As[128][32];
  __shared__ __align__(16) ushort_t Bs[128][32];
  const int K = 2048, N = 2048;
  int tid = threadIdx.x;
  int m0 = blockIdx.y * 128, n0 = blockIdx.x * 128;
  int w = tid >> 6, lane = tid & 63;
  int wm = (w >> 1) * 64, wn = (w & 1) * 64;
  int lr = lane & 15, quad = lane >> 4;
  int srow = lane >> 2, soff = (lane & 3) * 16;
  floatx4 acc[4][4] = {};
  for (int kt = 0; kt < 64; kt++) {
    __syncthreads();
#pragma unroll
    for (int j = 0; j < 2; j++) {
      int r = j * 64 + w * 16;
      ld_lds16((const char*)(ctx + (size_t)(m0 + r + srow) * K) + kt * 64 + soff,
               (char*)As + r * 64);
      ld_lds16((const char*)(WoT + (size_t)(n0 + r + srow) * K) + kt * 64 + soff,
               (char*)Bs + r * 64);
    }
    __syncthreads();
    short8 af[4], bf[4];
#pragma unroll
    for (int i = 0; i < 4; i++) af[i] = *(const short8*)(&As[wm + i * 16 + lr][quad * 8]);
#pragma unroll
    for (int j = 0; j < 4; j++) bf[j] = *(const short8*)(&Bs[wn + j * 16 + lr][quad * 8]);
#pragma unroll
    for (int i = 0; i < 4; i++)
#pragma unroll
      for (int j = 0; j < 4; j++)
        acc[i][j] = __builtin_amdgcn_mfma_f32_16x16x32_bf16(af[i], bf[j], acc[i][j], 0, 0, 0);
  }
#pragma unroll
  for (int i = 0; i < 4; i++)
#pragma unroll
    for (int j = 0; j < 4; j++) {
      int row = m0 + wm + i * 16 + quad * 4;
      int col = n0 + wn + j * 16 + lr;
#pragma unroll
      for (int r = 0; r < 4; r++)
        y[(size_t)(row + r) * N + col] = acc[i][j][r];
    }
}

// ---------------- MFMA flash attention v3: barrier-free, paired qtiles ----------------
// qbf (B,S,NH,HD) bf16 roped (in-place ctx out); kbf (B,NKV,S,HD); vt (B,NKV,HD,S).
// grid (16, 64): block pairs qtiles (i, 31-i) -> uniform 33 subtiles/block.
// K/V fragments read DIRECTLY from global (L2-served). LDS: per-wave P only, no barriers.
__global__ __launch_bounds__(256) void attn3(ushort_t* __restrict__ q,
                                             const ushort_t* __restrict__ k,
                                             const ushort_t* __restrict__ vt) {
  __shared__ __align__(16) ushort_t Ps[4][16][72];
  const float c2 = 0.18033688f;  // 0.125 * log2(e)
  int qa = blockIdx.x, qb = 31 - qa;
  int bh = blockIdx.y;
  int b = bh >> 5, h = bh & 31, g = h >> 2;
  int tid = threadIdx.x;
  int w = tid >> 6, lane = tid & 63;
  int lr = lane & 15, quad = lane >> 4;

  int qgA = qa * 64 + w * 16 + lr;
  int qgB = qb * 64 + w * 16 + lr;
  const ushort_t* qpA = q + ((size_t)(b * S_ + qgA) * NH + h) * HD;
  const ushort_t* qpB = q + ((size_t)(b * S_ + qgB) * NH + h) * HD;
  short8 aqA0 = *(const short8*)(qpA + quad * 8);
  short8 aqA1 = *(const short8*)(qpA + 32 + quad * 8);
  short8 aqB0 = *(const short8*)(qpB + quad * 8);
  short8 aqB1 = *(const short8*)(qpB + 32 + quad * 8);

  floatx4 odA[4] = {}, odB[4] = {};
  float miA = -INFINITY, liA = 0.f, miB = -INFINITY, liB = 0.f;
  size_t kbase = (size_t)(b * NKV + g) * S_ * HD;   // (B,NKV,S,HD)
  size_t vbase = (size_t)(b * NKV + g) * HD * S_;   // (B,NKV,HD,S)

  short8 kf[8], vf[8];

  auto process = [&](short8 q0, short8 q1, floatx4* od, float& mi, float& li,
                     int qg, bool diag, int t) {
    floatx4 sc[4];
#pragma unroll
    for (int kn = 0; kn < 4; kn++) {
      floatx4 c = {};
      c = __builtin_amdgcn_mfma_f32_16x16x32_bf16(kf[kn * 2], q0, c, 0, 0, 0);
      c = __builtin_amdgcn_mfma_f32_16x16x32_bf16(kf[kn * 2 + 1], q1, c, 0, 0, 0);
      sc[kn] = c;
    }
    float pv[16];
    float mx = -INFINITY;
#pragma unroll
    for (int kn = 0; kn < 4; kn++)
#pragma unroll
      for (int r = 0; r < 4; r++) {
        float s = sc[kn][r] * c2;               // log2 domain
        int kg = t * 64 + kn * 16 + quad * 4 + r;
        if (diag && kg > qg) s = -INFINITY;
        pv[kn * 4 + r] = s;
        mx = fmaxf(mx, s);
      }
    mx = fmaxf(mx, __shfl_xor(mx, 16));
    mx = fmaxf(mx, __shfl_xor(mx, 32));
    float mn = fmaxf(mi, mx);
    float al = exp2f(mi - mn);
    float ps = 0.f;
#pragma unroll
    for (int e = 0; e < 16; e++) {
      pv[e] = exp2f(pv[e] - mn);
      ps += pv[e];
    }
    ps += __shfl_xor(ps, 16);
    ps += __shfl_xor(ps, 32);
    li = li * al + ps;
    mi = mn;
#pragma unroll
    for (int dn = 0; dn < 4; dn++) {
      od[dn][0] *= al; od[dn][1] *= al; od[dn][2] *= al; od[dn][3] *= al;
    }
#pragma unroll
    for (int kn = 0; kn < 4; kn++) {
      short4v u;
      u[0] = (short)f2bfc(pv[kn * 4 + 0]); u[1] = (short)f2bfc(pv[kn * 4 + 1]);
      u[2] = (short)f2bfc(pv[kn * 4 + 2]); u[3] = (short)f2bfc(pv[kn * 4 + 3]);
      *(short4v*)(&Ps[w][lr][kn * 16 + quad * 4]) = u;
    }
    short8 pb0 = *(const short8*)(&Ps[w][lr][quad * 8]);        // in-wave LDS order
    short8 pb1 = *(const short8*)(&Ps[w][lr][32 + quad * 8]);
#pragma unroll
    for (int dn = 0; dn < 4; dn++) {
      od[dn] = __builtin_amdgcn_mfma_f32_16x16x32_bf16(vf[dn * 2], pb0, od[dn], 0, 0, 0);
      od[dn] = __builtin_amdgcn_mfma_f32_16x16x32_bf16(vf[dn * 2 + 1], pb1, od[dn], 0, 0, 0);
    }
  };

  for (int t = 0; t <= qb; t++) {
    const ushort_t* kp = k + kbase + (size_t)(t * 64) * HD;
#pragma unroll
    for (int kn = 0; kn < 4; kn++) {
      kf[kn * 2] = *(const short8*)(kp + (kn * 16 + lr) * HD + quad * 8);
      kf[kn * 2 + 1] = *(const short8*)(kp + (kn * 16 + lr) * HD + 32 + quad * 8);
    }
    const ushort_t* vp = vt + vbase + t * 64;
#pragma unroll
    for (int dn = 0; dn < 4; dn++) {
      vf[dn * 2] = *(const short8*)(vp + (size_t)(dn * 16 + lr) * S_ + quad * 8);
      vf[dn * 2 + 1] = *(const short8*)(vp + (size_t)(dn * 16 + lr) * S_ + 32 + quad * 8);
    }
    process(aqB0, aqB1, odB, miB, liB, qgB, t == qb, t);
    if (t <= qa) process(aqA0, aqA1, odA, miA, liA, qgA, t == qa, t);
  }

  float invA = 1.f / liA, invB = 1.f / liB;
  ushort_t* opA = q + ((size_t)(b * S_ + qgA) * NH + h) * HD;
  ushort_t* opB = q + ((size_t)(b * S_ + qgB) * NH + h) * HD;
#pragma unroll
  for (int dn = 0; dn < 4; dn++) {
    short4v uA, uB;
    uA[0] = (short)f2bfc(odA[dn][0] * invA); uA[1] = (short)f2bfc(odA[dn][1] * invA);
    uA[2] = (short)f2bfc(odA[dn][2] * invA); uA[3] = (short)f2bfc(odA[dn][3] * invA);
    uB[0] = (short)f2bfc(odB[dn][0] * invB); uB[1] = (short)f2bfc(odB[dn][1] * invB);
    uB[2] = (short)f2bfc(odB[dn][2] * invB); uB[3] = (short)f2bfc(odB[dn][3] * invB);
    *(short4v*)(opA + dn * 16 + quad * 4) = uA;
    *(short4v*)(opB + dn * 16 + quad * 4) = uB;
  }
}

extern "C" void kernel_launch(void* const* d_in, const int* in_sizes, int n_in,
                              void* d_out, int out_size, void* d_ws, size_t ws_size,
                              hipStream_t stream) {
  const float* x = (const float*)d_in[0];
  const float* cosT = (const float*)d_in[2];
  const float* sinT = (const float*)d_in[3];
  const float* Wq = (const float*)d_in[4];
  const float* Wk = (const float*)d_in[5];
  const float* Wv = (const float*)d_in[6];
  const float* Wo = (const float*)d_in[7];

  char* ws = (char*)d_ws;
  ushort_t* WT = (ushort_t*)(ws);                 // 12 MB (3072,2048): Wq^T|Wk^T|Wv^T
  ushort_t* WoT = (ushort_t*)(ws + 12582912);     //  8 MB (2048,2048)
  ushort_t* xb = (ushort_t*)(ws + 20971520);      // 16 MB (M,2048) bf16
  ushort_t* qbf = (ushort_t*)(ws + 37748736);     // 16 MB (B,S,NH,HD); ctx in-place
  ushort_t* kbf = (ushort_t*)(ws + 54525952);     //  4 MB (B,NKV,S,HD)
  ushort_t* vt = (ushort_t*)(ws + 58720256);      //  4 MB (B,NKV,HD,S) -> 60 MB total

  float* y = (float*)d_out;                            // (B,S,E) fp32
  float* outk = y + (size_t)M_ * E_;                   // (B,NKV,S,HD) fp32
  float* outv = outk + (size_t)B_ * NKV * S_ * HD;     // (B,NKV,S,HD) fp32

  cast_x<<<dim3(4096), 256, 0, stream>>>(x, xb);
  transpose_all<<<dim3(160, 64), dim3(32, 8), 0, stream>>>(Wq, Wk, Wv, Wo, WT, WoT);

  gemm_qkv<<<dim3(24, 32), 256, 0, stream>>>(xb, WT, qbf, outk, kbf, outv, cosT, sinT);
  transpose_v<<<dim3(32, 16), 256, 0, stream>>>(outv, vt);

  attn3<<<dim3(16, 64), 256, 0, stream>>>(qbf, kbf, vt);

  gemm_o<<<dim3(16, 32), 256, 0, stream>>>(qbf, WoT, y);
}